// Round 3
// baseline (585.020 us; speedup 1.0000x reference)
//
#include <hip/hip_runtime.h>
#include <stdint.h>
#include <stddef.h>

// ---------------------------------------------------------------------------
// EquivariantCorrectionHead on MI355X — fp32, low-workspace (7.8 MB) version.
//
//   y0[z,w]  = sum_p Bsym[p,w] * P[z,p]      P = sym outer(s,s) ++ Gram(t)
//              (Bsym generated on the fly from W000/W220 in the GEMM)
//   y2[z,k,w]= (s@W1)-contract(t) + C2 * W222 . (t x C222 x t)   [fused, LDS]
//   ac'      = y0 @ VBs           VBs = C2B/sqrt5 * (V022 + V202^T)
//   out[z,k] = sum_v ac'[z,v] y2[z,k,v]
//            + sum_{i,j} C222[i,j,k] * (y2[z,i,:] . VC . y2[z,j,:])
// ---------------------------------------------------------------------------

#define NS     128
#define NL2    8
#define HH     256

#define KPAIR  8256          // NS*(NS+1)/2
#define KPAD   8448          // 16 splits * 33 tiles * 16
#define GLEN   64            // Gram region per z (36 used, rest zero)
#define KSPLIT 16
#define CHUNK  528
#define KT     16
#define NTILES 33

#define C0F  0.00779729f     // sqrt(1/(128^2+8^2))
#define C2F  0.04865619f     // sqrt(5/(2*128*8+64))
#define C2BF 0.005042948f    // sqrt(5/(3*256^2))
#define IS5  0.44721360f     // 1/sqrt(5)

// workspace offsets (floats)
constexpr size_t OFF_C222 = 0;            // 128
constexpr size_t OFF_PU   = 128;          // 8448 (int)
constexpr size_t OFF_PV   = 8576;         // 8448 (int)
constexpr size_t OFF_T    = 17024;        // 2048*40
constexpr size_t OFF_GSYM = 98944;        // 2048*64
constexpr size_t OFF_W1   = 230016;       // 128*4096
constexpr size_t OFF_W222 = 754304;       // 16384
constexpr size_t OFF_VBS  = 770688;       // 256*256
constexpr size_t OFF_VC   = 836224;       // 256*256
constexpr size_t OFF_Y0   = 901760;       // 2048*256
constexpr size_t OFF_ACP  = 1426048;      // 2048*256
constexpr size_t WS_FLOATS = 1950336;     // ~7.8 MB

// prep segment boundaries
#define SEG_T    81920
#define SEG_PUV  90368      // +8448
#define SEG_W1   614656     // +524288
#define SEG_W222 631040     // +16384
#define SEG_VBS  696576     // +65536
#define SEG_VC   762112     // +65536
#define SEG_GS   893184     // +131072
#define SEG_Y0   1417472    // +524288

// ---------------------------------------------------------------------------
// prep: c222 (block 0) + t, pair tables, W1, W222c, VBs, VC, Gsym, y0=0
// ---------------------------------------------------------------------------
__global__ __launch_bounds__(256) void prep_k(
    const float* __restrict__ kt2s, const float* __restrict__ W022,
    const float* __restrict__ W202, const float* __restrict__ W222,
    const float* __restrict__ V022, const float* __restrict__ V202,
    const float* __restrict__ V222, float* __restrict__ ws) {
  const int tid = threadIdx.x;

  if (blockIdx.x == 0) {
    // real-basis Wigner 3j (2,2,2), Frobenius-normalized (matches reference)
    __shared__ float cv[125];
    __shared__ float inv;
    float val = 0.f;
    if (tid < 125) {
      float Q[45];
      #pragma unroll
      for (int q = 0; q < 45; ++q) Q[q] = 0.f;
      const float s2 = 0.70710678f, s6 = 0.40824829f;
      Q[0*9+0*3+1] = s2;  Q[0*9+1*3+0] = s2;
      Q[1*9+1*3+2] = s2;  Q[1*9+2*3+1] = s2;
      Q[2*9+0*3+0] = -s6; Q[2*9+1*3+1] = -s6; Q[2*9+2*3+2] = 2.f*s6;
      Q[3*9+0*3+2] = s2;  Q[3*9+2*3+0] = s2;
      Q[4*9+0*3+0] = s2;  Q[4*9+1*3+1] = -s2;
      const int a = tid/25, b = (tid/5)%5, c = tid%5;
      for (int i = 0; i < 3; ++i)
        for (int j = 0; j < 3; ++j)
          for (int k = 0; k < 3; ++k)
            val += Q[a*9+i*3+j]*Q[b*9+j*3+k]*Q[c*9+k*3+i];
      cv[tid] = val;
    }
    __syncthreads();
    if (tid == 0) {
      float sq = 0.f;
      for (int p = 0; p < 125; ++p) sq += cv[p]*cv[p];
      inv = 1.0f/sqrtf(sq);
    }
    __syncthreads();
    if (tid < 125) ws[OFF_C222 + tid] = val*inv;
    return;
  }

  int*   pu    = (int*)(ws + OFF_PU);
  int*   pv    = (int*)(ws + OFF_PV);
  const int stride = (gridDim.x - 1)*256;
  for (int i = (blockIdx.x - 1)*256 + tid; i < SEG_Y0; i += stride) {
    if (i < SEG_T) {                      // t[z,u,i]
      int z = i/40, r = i - z*40, u = r/5, ii = r - u*5;
      float v;
      if (u < 7) v = kt2s[z*40 + u*5 + ii];
      else {
        v = 0.f;
        for (int k = 0; k < 8; ++k) v += kt2s[z*40 + k*5 + ii];
      }
      ws[OFF_T + i] = v;
    } else if (i < SEG_PUV) {             // pair decode tables
      int p = i - SEG_T;
      int u = 0, vv = 0;
      if (p < KPAIR) {
        int rem = p;
        while (rem >= NS - u) { rem -= NS - u; ++u; }
        vv = u + rem;
      } else if (p < KPAIR + 36) {
        int q = p - KPAIR;
        while (q >= NL2 - u) { q -= NL2 - u; ++u; }
        vv = u + q;
      }
      pu[p] = u; pv[p] = vv;
    } else if (i < SEG_W1) {              // W1 = [W022 | W202^T] * C2/sqrt5
      int j = i - SEG_PUV;
      int u = j >> 12, col = j & 4095;
      float v;
      if (col < 2048) {
        int vv = col >> 8, w = col & 255;
        v = (C2F*IS5)*W022[(u*NL2 + vv)*HH + w];
      } else {
        int u2 = (col - 2048) >> 8, w = col & 255;
        v = (C2F*IS5)*W202[(u2*NS + u)*HH + w];
      }
      ws[OFF_W1 + j] = v;
    } else if (i < SEG_W222) {            // W222 * C2
      int j = i - SEG_W1;
      ws[OFF_W222 + j] = C2F*W222[j];
    } else if (i < SEG_VBS) {             // VBs = C2B/sqrt5*(V022 + V202^T)
      int j = i - SEG_W222;
      int u = j >> 8, c = j & 255;
      ws[OFF_VBS + j] = (C2BF*IS5)*(V022[u*HH + c] + V202[c*HH + u]);
    } else if (i < SEG_VC) {              // VC = C2B * V222
      int j = i - SEG_VBS;
      ws[OFF_VC + j] = C2BF*V222[j];
    } else if (i < SEG_GS) {              // Gram of t (36 entries, pad 0)
      int j = i - SEG_VC;
      int z = j >> 6, q = j & 63;
      float v = 0.f;
      if (q < 36) {
        int qq = q, u = 0;
        while (qq >= NL2 - u) { qq -= NL2 - u; ++u; }
        int vv = u + qq;
        const float* kz = kt2s + (size_t)z*40;
        #pragma unroll
        for (int ii = 0; ii < 5; ++ii) {
          float tu, tv;
          if (u < 7) tu = kz[u*5 + ii];
          else { tu = 0.f; for (int k = 0; k < 8; ++k) tu += kz[k*5 + ii]; }
          if (vv < 7) tv = kz[vv*5 + ii];
          else { tv = 0.f; for (int k = 0; k < 8; ++k) tv += kz[k*5 + ii]; }
          v += tu*tv;
        }
      }
      ws[OFF_GSYM + j] = v;
    } else {                              // y0 = 0
      ws[OFF_Y0 + (i - SEG_GS)] = 0.f;
    }
  }
}

// ---------------------------------------------------------------------------
// y0 GEMM: M=2048 N=256 K=KPAD. A generated from s/Gsym; B symmetrized on the
// fly from W000/W220. tile 64x256, KT=16, split-K=16 via fp32 atomics.
// ---------------------------------------------------------------------------
__global__ __launch_bounds__(256) void gemm_y0_k(
    const float* __restrict__ s, const float* __restrict__ W000,
    const float* __restrict__ W220, float* __restrict__ ws) {
  const int* pu = (const int*)(ws + OFF_PU);
  const int* pv = (const int*)(ws + OFF_PV);
  const float* Gsym = ws + OFF_GSYM;
  float* y0 = ws + OFF_Y0;

  __shared__ float s_s[64][129];
  __shared__ __align__(16) float As[KT][64];
  __shared__ __align__(16) float Bs[KT][256];

  const int tid  = threadIdx.x;
  const int ks   = blockIdx.x & 15, mt = blockIdx.x >> 4;
  const int z0   = mt*64;
  const int kbase = ks*CHUNK;
  const int lane = tid & 63, wave = tid >> 6;
  const int tx   = tid & 31, ty   = tid >> 5;

  for (int e = 0; e < 8; ++e) {                 // stage s tile (64x128)
    int f4 = e*256 + tid;
    int row = f4 >> 5, c4 = f4 & 31;
    float4 v = reinterpret_cast<const float4*>(s + (size_t)(z0 + row)*NS)[c4];
    s_s[row][c4*4+0] = v.x; s_s[row][c4*4+1] = v.y;
    s_s[row][c4*4+2] = v.z; s_s[row][c4*4+3] = v.w;
  }

  float acc[8][8];
  #pragma unroll
  for (int i = 0; i < 8; ++i)
    #pragma unroll
    for (int j = 0; j < 8; ++j) acc[i][j] = 0.f;

  for (int tt = 0; tt < NTILES; ++tt) {
    const int k0 = kbase + tt*KT;
    __syncthreads();
    #pragma unroll
    for (int e = 0; e < 4; ++e) {               // stage B tile (symmetrized)
      int row = e*4 + wave;                     // wave-uniform
      int p = k0 + row;
      float4 val;
      if (p < KPAIR) {
        int u = pu[p], v = pv[p];
        float4 a = *reinterpret_cast<const float4*>(&W000[((size_t)(u*NS + v))*HH + lane*4]);
        if (u != v) {
          float4 b = *reinterpret_cast<const float4*>(&W000[((size_t)(v*NS + u))*HH + lane*4]);
          val = make_float4(C0F*(a.x+b.x), C0F*(a.y+b.y), C0F*(a.z+b.z), C0F*(a.w+b.w));
        } else {
          val = make_float4(C0F*a.x, C0F*a.y, C0F*a.z, C0F*a.w);
        }
      } else if (p < KPAIR + 36) {
        int u = pu[p], v = pv[p];
        const float sc = C0F*IS5;
        float4 a = *reinterpret_cast<const float4*>(&W220[(u*NL2 + v)*HH + lane*4]);
        if (u != v) {
          float4 b = *reinterpret_cast<const float4*>(&W220[(v*NL2 + u)*HH + lane*4]);
          val = make_float4(sc*(a.x+b.x), sc*(a.y+b.y), sc*(a.z+b.z), sc*(a.w+b.w));
        } else {
          val = make_float4(sc*a.x, sc*a.y, sc*a.z, sc*a.w);
        }
      } else {
        val = make_float4(0.f, 0.f, 0.f, 0.f);
      }
      *reinterpret_cast<float4*>(&Bs[row][lane*4]) = val;
    }
    #pragma unroll
    for (int e = 0; e < 4; ++e) {               // generate A tile 16x64
      int kk = e*4 + wave;
      int k = k0 + kk;
      float a;
      if (k < KPAIR) a = s_s[lane][pu[k]]*s_s[lane][pv[k]];
      else {
        int q = k - KPAIR;
        a = (q < GLEN) ? Gsym[(size_t)(z0 + lane)*GLEN + q] : 0.f;
      }
      As[kk][lane] = a;
    }
    __syncthreads();
    #pragma unroll
    for (int kk = 0; kk < KT; ++kk) {
      float4 a0 = *reinterpret_cast<const float4*>(&As[kk][ty*8]);
      float4 a1 = *reinterpret_cast<const float4*>(&As[kk][ty*8+4]);
      float4 b0 = *reinterpret_cast<const float4*>(&Bs[kk][tx*4]);
      float4 b1 = *reinterpret_cast<const float4*>(&Bs[kk][128 + tx*4]);
      float am[8] = {a0.x,a0.y,a0.z,a0.w,a1.x,a1.y,a1.z,a1.w};
      float bn[8] = {b0.x,b0.y,b0.z,b0.w,b1.x,b1.y,b1.z,b1.w};
      #pragma unroll
      for (int mi = 0; mi < 8; ++mi)
        #pragma unroll
        for (int ni = 0; ni < 8; ++ni)
          acc[mi][ni] += am[mi]*bn[ni];
    }
  }
  #pragma unroll
  for (int mi = 0; mi < 8; ++mi) {
    int z = z0 + ty*8 + mi;
    #pragma unroll
    for (int ni = 0; ni < 8; ++ni) {
      int col = (ni < 4) ? (tx*4 + ni) : (128 + tx*4 + (ni-4));
      atomicAdd(&y0[(size_t)z*HH + col], acc[mi][ni]);
    }
  }
}

// ---------------------------------------------------------------------------
// generic fp32 GEMM, row-major, C = A@B. tiles 64x64, KT=32.
// ---------------------------------------------------------------------------
__global__ __launch_bounds__(256) void gemm_rm_k(
    const float* __restrict__ A, const float* __restrict__ B,
    float* __restrict__ C, int M, int N, int K) {
  __shared__ __align__(16) float As[32][68];
  __shared__ __align__(16) float Bs[32][68];
  const int tid = threadIdx.x, tx = tid & 15, ty = tid >> 4;
  const int n0 = blockIdx.x*64, m0 = blockIdx.y*64;
  float acc[4][4];
  #pragma unroll
  for (int i = 0; i < 4; ++i)
    #pragma unroll
    for (int j = 0; j < 4; ++j) acc[i][j] = 0.f;

  for (int k0 = 0; k0 < K; k0 += 32) {
    __syncthreads();
    #pragma unroll
    for (int e = 0; e < 2; ++e) {
      int r = e*32 + (tid >> 3);
      int kc = (tid & 7)*4;
      float4 v = *reinterpret_cast<const float4*>(&A[(size_t)(m0+r)*K + k0 + kc]);
      As[kc+0][r] = v.x; As[kc+1][r] = v.y; As[kc+2][r] = v.z; As[kc+3][r] = v.w;
    }
    #pragma unroll
    for (int e = 0; e < 2; ++e) {
      int idx = e*256 + tid;
      int r = idx >> 4, c4 = idx & 15;
      float4 v = *reinterpret_cast<const float4*>(&B[(size_t)(k0+r)*N + n0 + c4*4]);
      *reinterpret_cast<float4*>(&Bs[r][c4*4]) = v;
    }
    __syncthreads();
    #pragma unroll
    for (int kk = 0; kk < 32; ++kk) {
      float4 av = *reinterpret_cast<const float4*>(&As[kk][ty*4]);
      float4 bv = *reinterpret_cast<const float4*>(&Bs[kk][tx*4]);
      float am[4] = {av.x, av.y, av.z, av.w};
      float bn[4] = {bv.x, bv.y, bv.z, bv.w};
      #pragma unroll
      for (int i = 0; i < 4; ++i)
        #pragma unroll
        for (int j = 0; j < 4; ++j) acc[i][j] += am[i]*bn[j];
    }
  }
  #pragma unroll
  for (int i = 0; i < 4; ++i) {
    float4 v = make_float4(acc[i][0], acc[i][1], acc[i][2], acc[i][3]);
    *reinterpret_cast<float4*>(&C[(size_t)(m0 + ty*4 + i)*N + n0 + tx*4]) = v;
  }
}

// ---------------------------------------------------------------------------
// mega: per 8-z block, fused y2 (A12-part + W222 term) + tp2 tail -> out[z,5]
// ---------------------------------------------------------------------------
__global__ __launch_bounds__(256) void mega_k(
    const float* __restrict__ scalars, const float* __restrict__ ws,
    float* __restrict__ out) {
  const float* tg    = ws + OFF_T;
  const float* W1    = ws + OFF_W1;
  const float* W222c = ws + OFF_W222;
  const float* VC    = ws + OFF_VC;
  const float* acp   = ws + OFF_ACP;
  const float* c222g = ws + OFF_C222;

  __shared__ float ts[8][40];
  __shared__ float c2s[125];
  __shared__ __align__(16) float sb[8][128];
  __shared__ __align__(16) float ovl[10240];   // tC[1600] + Rs[2560] | y2s[10240]
  float* tC  = ovl;                 // tC(z,v,ik)   = tC[z*200 + v*25 + ik]
  float* RsF = ovl + 1600;          // Rs(uv,z,k)   = RsF[uv*40 + z*5 + k]
  float* y2s = ovl;                 // y2(z,i,u)    = y2s[z*1280 + i*256 + u]

  const int tid = threadIdx.x;
  const int zg0 = blockIdx.x*8;
  const int lane = tid & 63, wv = tid >> 6;

  // stage ts, c2s, sb   (ts is 320 entries > blockDim: MUST grid-stride)
  if (tid < 125) c2s[tid] = c222g[tid];
  for (int r = tid; r < 320; r += 256) {
    int z = r/40, c = r - z*40;
    ts[z][c] = tg[(size_t)(zg0 + z)*40 + c];
  }
  {
    int z = tid >> 5, c4 = tid & 31;
    float4 v = reinterpret_cast<const float4*>(scalars + (size_t)(zg0 + z)*NS)[c4];
    sb[z][c4*4+0] = v.x; sb[z][c4*4+1] = v.y;
    sb[z][c4*4+2] = v.z; sb[z][c4*4+3] = v.w;
  }
  __syncthreads();

  for (int idx = tid; idx < 1600; idx += 256) {    // tC = C222 . t
    int z = idx/200, r = idx - z*200, v = r/25, ik = r - v*25;
    int i = ik/5, k = ik - i*5;
    float a = 0.f;
    #pragma unroll
    for (int j = 0; j < 5; ++j) a += c2s[(i*5+j)*5 + k]*ts[z][v*5+j];
    tC[idx] = a;
  }
  __syncthreads();
  for (int idx = tid; idx < 2560; idx += 256) {    // Rs = t x C222 x t
    int uv = idx/40, r = idx - uv*40, z = r/5, k = r - z*5;
    int u = uv >> 3, v = uv & 7;
    float a = 0.f;
    #pragma unroll
    for (int ii = 0; ii < 5; ++ii) a += ts[z][u*5+ii]*tC[z*200 + v*25 + ii*5 + k];
    RsF[idx] = a;
  }
  __syncthreads();

  float acc[8][5];                                 // y2[z,k, w=tid]
  #pragma unroll
  for (int z = 0; z < 8; ++z)
    #pragma unroll
    for (int k = 0; k < 5; ++k) acc[z][k] = 0.f;

  // fused A12 part: sum_u s[z,u]*W1[u, vp*256+tid], contracted with t
  for (int vg = 0; vg < 4; ++vg) {
    float av[4][8];
    #pragma unroll
    for (int vi = 0; vi < 4; ++vi)
      #pragma unroll
      for (int z = 0; z < 8; ++z) av[vi][z] = 0.f;
    for (int u4 = 0; u4 < 128; u4 += 4) {
      float4 szv[8];
      #pragma unroll
      for (int z = 0; z < 8; ++z) szv[z] = *reinterpret_cast<const float4*>(&sb[z][u4]);
      #pragma unroll
      for (int uu = 0; uu < 4; ++uu) {
        #pragma unroll
        for (int vi = 0; vi < 4; ++vi) {
          float w1v = W1[(size_t)(u4+uu)*4096 + (vg*4+vi)*256 + tid];
          #pragma unroll
          for (int z = 0; z < 8; ++z) {
            float su = (uu==0)?szv[z].x:(uu==1)?szv[z].y:(uu==2)?szv[z].z:szv[z].w;
            av[vi][z] += su*w1v;
          }
        }
      }
    }
    #pragma unroll
    for (int vi = 0; vi < 4; ++vi) {
      int vmap = (vg*4 + vi) & 7;
      #pragma unroll
      for (int z = 0; z < 8; ++z)
        #pragma unroll
        for (int k = 0; k < 5; ++k)
          acc[z][k] += av[vi][z]*ts[z][vmap*5+k];
    }
  }

  // W222 term
  for (int uv = 0; uv < 64; ++uv) {
    float wvv = W222c[uv*256 + tid];
    #pragma unroll
    for (int c4 = 0; c4 < 10; ++c4) {
      float4 rv = *reinterpret_cast<const float4*>(&RsF[uv*40 + c4*4]);
      acc[(c4*4+0)/5][(c4*4+0)%5] += wvv*rv.x;
      acc[(c4*4+1)/5][(c4*4+1)%5] += wvv*rv.y;
      acc[(c4*4+2)/5][(c4*4+2)%5] += wvv*rv.z;
      acc[(c4*4+3)/5][(c4*4+3)%5] += wvv*rv.w;
    }
  }

  __syncthreads();                                 // tC/Rs dead; overlay
  #pragma unroll
  for (int z = 0; z < 8; ++z)
    #pragma unroll
    for (int k = 0; k < 5; ++k)
      y2s[z*1280 + k*256 + tid] = acc[z][k];
  __syncthreads();

  // Hz[z,i,v] = sum_u y2[z,i,u]*VC[u,v]; wave wv owns z = wv*2 + {0,1},
  // lane covers v = lane + 64*j
  float hacc[2][5][4];
  #pragma unroll
  for (int zz = 0; zz < 2; ++zz)
    #pragma unroll
    for (int i = 0; i < 5; ++i)
      #pragma unroll
      for (int j = 0; j < 4; ++j) hacc[zz][i][j] = 0.f;

  for (int u4 = 0; u4 < 256; u4 += 4) {
    float vc[4][4];
    #pragma unroll
    for (int uu = 0; uu < 4; ++uu)
      #pragma unroll
      for (int j = 0; j < 4; ++j)
        vc[uu][j] = VC[(size_t)(u4+uu)*256 + lane + 64*j];
    #pragma unroll
    for (int zz = 0; zz < 2; ++zz) {
      int z = wv*2 + zz;
      #pragma unroll
      for (int i = 0; i < 5; ++i) {
        float4 yv = *reinterpret_cast<const float4*>(&y2s[z*1280 + i*256 + u4]);
        float ya[4] = {yv.x, yv.y, yv.z, yv.w};
        #pragma unroll
        for (int uu = 0; uu < 4; ++uu)
          #pragma unroll
          for (int j = 0; j < 4; ++j)
            hacc[zz][i][j] += ya[uu]*vc[uu][j];
      }
    }
  }

  // out[z,k] = sum_v ac'[z,v]*y2[z,k,v] + sum_{i,jp} C[i,jp,k]*Hz[z,i,v]*y2[z,jp,v]
  float outp[2][5];
  #pragma unroll
  for (int zz = 0; zz < 2; ++zz)
    #pragma unroll
    for (int k = 0; k < 5; ++k) outp[zz][k] = 0.f;

  for (int j = 0; j < 4; ++j) {
    int v = lane + 64*j;
    #pragma unroll
    for (int zz = 0; zz < 2; ++zz) {
      int z = wv*2 + zz;
      float y2v[5];
      #pragma unroll
      for (int jp = 0; jp < 5; ++jp) y2v[jp] = y2s[z*1280 + jp*256 + v];
      float avv = acp[(size_t)(zg0 + z)*256 + v];
      #pragma unroll
      for (int k = 0; k < 5; ++k) outp[zz][k] += avv*y2v[k];
      #pragma unroll
      for (int i = 0; i < 5; ++i) {
        float hv = hacc[zz][i][j];
        #pragma unroll
        for (int jp = 0; jp < 5; ++jp) {
          float pj = hv*y2v[jp];
          #pragma unroll
          for (int k = 0; k < 5; ++k)
            outp[zz][k] += pj*c2s[i*25 + jp*5 + k];
        }
      }
    }
  }

  #pragma unroll
  for (int zz = 0; zz < 2; ++zz)
    #pragma unroll
    for (int k = 0; k < 5; ++k) {
      float vsum = outp[zz][k];
      #pragma unroll
      for (int off = 32; off > 0; off >>= 1) vsum += __shfl_xor(vsum, off, 64);
      if (lane == 0) out[(size_t)(zg0 + wv*2 + zz)*5 + k] = vsum;
    }
}

// ---------------------------------------------------------------------------
extern "C" void kernel_launch(void* const* d_in, const int* in_sizes, int n_in,
                              void* d_out, int out_size, void* d_ws, size_t ws_size,
                              hipStream_t stream) {
  (void)in_sizes; (void)n_in; (void)out_size;
  const float* scalars = (const float*)d_in[0];
  const float* kt2s    = (const float*)d_in[1];
  const float* W000    = (const float*)d_in[2];
  const float* W220    = (const float*)d_in[3];
  const float* W022    = (const float*)d_in[4];
  const float* W202    = (const float*)d_in[5];
  const float* W222    = (const float*)d_in[6];
  const float* V022    = (const float*)d_in[7];
  const float* V202    = (const float*)d_in[8];
  const float* V222    = (const float*)d_in[9];
  float* out = (float*)d_out;
  float* ws  = (float*)d_ws;
  if (ws_size < WS_FLOATS*sizeof(float)) return;  // needs ~7.8 MB scratch

  prep_k<<<1025, 256, 0, stream>>>(kt2s, W022, W202, W222, V022, V202, V222, ws);
  gemm_y0_k<<<512, 256, 0, stream>>>(scalars, W000, W220, ws);
  gemm_rm_k<<<dim3(4, 32), 256, 0, stream>>>(ws + OFF_Y0, ws + OFF_VBS,
                                             (float*)(ws + OFF_ACP), 2048, 256, 256);
  mega_k<<<256, 256, 0, stream>>>(scalars, ws, out);
}

// Round 4
// 498.149 us; speedup vs baseline: 1.1744x; 1.1744x over previous
//
#include <hip/hip_runtime.h>
#include <stdint.h>
#include <stddef.h>

// ---------------------------------------------------------------------------
// EquivariantCorrectionHead on MI355X — fp32, low-workspace (6.75 MB) version.
//
//   y0[z,w]  = sum_p Bsym[p,w] * P[z,p]      P = sym outer(s,s) ++ Gram(t)
//              (Bsym generated on the fly from W000/W220 in the GEMM;
//               A generated from sT/GramT — coalesced, no LDS s-tile)
//   y2[z,k,w]= (s@[W022|W202^T])-contract(t) + C2 * W222 . (t x C222 x t)
//   ac'      = y0 @ VBs           VBs = C2B/sqrt5 * (V022 + V202^T)
//   out[z,k] = sum_v ac'[z,v] y2[z,k,v]
//            + sum_{i,j} C222[i,j,k] * (y2[z,i,:] . VC . y2[z,j,:])
// ---------------------------------------------------------------------------

#define NS     128
#define NL2    8
#define HH     256
#define NB     2048

#define KPAIR  8256          // NS*(NS+1)/2
#define KPAD   8448          // 16 splits * 33 tiles * 16
#define GLEN   64            // Gram region per z (36 used, rest zero)
#define KSPLIT 16
#define CHUNK  528
#define KT     16
#define NTILES 33

#define C0F  0.00779729f     // sqrt(1/(128^2+8^2))
#define C2F  0.04865619f     // sqrt(5/(2*128*8+64))
#define C2BF 0.005042948f    // sqrt(5/(3*256^2))
#define IS5  0.44721360f     // 1/sqrt(5)

// workspace offsets (floats)
constexpr size_t OFF_C222 = 0;            // 128
constexpr size_t OFF_PU   = 128;          // 8448 (int)
constexpr size_t OFF_PV   = 8576;         // 8448 (int)
constexpr size_t OFF_T    = 17024;        // 2048*40
constexpr size_t OFF_W222 = 98944;        // 16384
constexpr size_t OFF_VBS  = 115328;       // 256*256
constexpr size_t OFF_VC   = 180864;       // 256*256
constexpr size_t OFF_ST   = 246400;       // 128*2048  (s transposed)
constexpr size_t OFF_GT   = 508544;       // 64*2048   (Gram transposed)
constexpr size_t OFF_Y0   = 639616;       // 2048*256
constexpr size_t OFF_ACP  = 1163904;      // 2048*256
constexpr size_t WS_FLOATS = 1688192;     // ~6.75 MB

// prep segment boundaries (element index space)
#define SEG_T    81920
#define SEG_PUV  90368      // +8448
#define SEG_W222 106752     // +16384
#define SEG_VBS  172288     // +65536
#define SEG_VC   237824     // +65536
#define SEG_ST   499968     // +262144
#define SEG_GT   631040     // +131072
#define SEG_END  1155328    // +524288 (y0 = 0)

// ---------------------------------------------------------------------------
// prep: c222 (block 0) + t, pair tables, W222c, VBs, VC, sT, GramT, y0=0
// ---------------------------------------------------------------------------
__global__ __launch_bounds__(256) void prep_k(
    const float* __restrict__ scalars, const float* __restrict__ kt2s,
    const float* __restrict__ W222,
    const float* __restrict__ V022, const float* __restrict__ V202,
    const float* __restrict__ V222, float* __restrict__ ws) {
  const int tid = threadIdx.x;

  if (blockIdx.x == 0) {
    // real-basis Wigner 3j (2,2,2), Frobenius-normalized (matches reference)
    __shared__ float cv[125];
    __shared__ float inv;
    float val = 0.f;
    if (tid < 125) {
      float Q[45];
      #pragma unroll
      for (int q = 0; q < 45; ++q) Q[q] = 0.f;
      const float s2 = 0.70710678f, s6 = 0.40824829f;
      Q[0*9+0*3+1] = s2;  Q[0*9+1*3+0] = s2;
      Q[1*9+1*3+2] = s2;  Q[1*9+2*3+1] = s2;
      Q[2*9+0*3+0] = -s6; Q[2*9+1*3+1] = -s6; Q[2*9+2*3+2] = 2.f*s6;
      Q[3*9+0*3+2] = s2;  Q[3*9+2*3+0] = s2;
      Q[4*9+0*3+0] = s2;  Q[4*9+1*3+1] = -s2;
      const int a = tid/25, b = (tid/5)%5, c = tid%5;
      for (int i = 0; i < 3; ++i)
        for (int j = 0; j < 3; ++j)
          for (int k = 0; k < 3; ++k)
            val += Q[a*9+i*3+j]*Q[b*9+j*3+k]*Q[c*9+k*3+i];
      cv[tid] = val;
    }
    __syncthreads();
    if (tid == 0) {
      float sq = 0.f;
      for (int p = 0; p < 125; ++p) sq += cv[p]*cv[p];
      inv = 1.0f/sqrtf(sq);
    }
    __syncthreads();
    if (tid < 125) ws[OFF_C222 + tid] = val*inv;
    return;
  }

  int* pu = (int*)(ws + OFF_PU);
  int* pv = (int*)(ws + OFF_PV);
  const int stride = (gridDim.x - 1)*256;
  for (int i = (blockIdx.x - 1)*256 + tid; i < SEG_END; i += stride) {
    if (i < SEG_T) {                      // t[z,u,i]
      int z = i/40, r = i - z*40, u = r/5, ii = r - u*5;
      float v;
      if (u < 7) v = kt2s[z*40 + u*5 + ii];
      else {
        v = 0.f;
        for (int k = 0; k < 8; ++k) v += kt2s[z*40 + k*5 + ii];
      }
      ws[OFF_T + i] = v;
    } else if (i < SEG_PUV) {             // pair decode tables
      int p = i - SEG_T;
      int u = 0, vv = 0;
      if (p < KPAIR) {
        int rem = p;
        while (rem >= NS - u) { rem -= NS - u; ++u; }
        vv = u + rem;
      } else if (p < KPAIR + 36) {
        int q = p - KPAIR;
        while (q >= NL2 - u) { q -= NL2 - u; ++u; }
        vv = u + q;
      }
      pu[p] = u; pv[p] = vv;
    } else if (i < SEG_W222) {            // W222 * C2
      int j = i - SEG_PUV;
      ws[OFF_W222 + j] = C2F*W222[j];
    } else if (i < SEG_VBS) {             // VBs = C2B/sqrt5*(V022 + V202^T)
      int j = i - SEG_W222;
      int u = j >> 8, c = j & 255;
      ws[OFF_VBS + j] = (C2BF*IS5)*(V022[u*HH + c] + V202[c*HH + u]);
    } else if (i < SEG_VC) {              // VC = C2B * V222
      int j = i - SEG_VBS;
      ws[OFF_VC + j] = C2BF*V222[j];
    } else if (i < SEG_ST) {              // sT[u][z]
      int j = i - SEG_VC;
      int u = j >> 11, z = j & 2047;
      ws[OFF_ST + j] = scalars[(size_t)z*NS + u];
    } else if (i < SEG_GT) {              // GramT[q][z] (36 real, rest 0)
      int j = i - SEG_ST;
      int q = j >> 11, z = j & 2047;
      float v = 0.f;
      if (q < 36) {
        int qq = q, u = 0;
        while (qq >= NL2 - u) { qq -= NL2 - u; ++u; }
        int vv = u + qq;
        const float* kz = kt2s + (size_t)z*40;
        #pragma unroll
        for (int ii = 0; ii < 5; ++ii) {
          float tu, tv;
          if (u < 7) tu = kz[u*5 + ii];
          else { tu = 0.f; for (int k = 0; k < 8; ++k) tu += kz[k*5 + ii]; }
          if (vv < 7) tv = kz[vv*5 + ii];
          else { tv = 0.f; for (int k = 0; k < 8; ++k) tv += kz[k*5 + ii]; }
          v += tu*tv;
        }
      }
      ws[OFF_GT + j] = v;
    } else {                              // y0 = 0
      ws[OFF_Y0 + (i - SEG_GT)] = 0.f;
    }
  }
}

// ---------------------------------------------------------------------------
// y0 GEMM: M=2048 N=256 K=KPAD. Tile 64x128, KT=16, split-K=16, grid 1024.
// A from sT/GramT (coalesced), B symmetrized on the fly from W000/W220.
// Double-buffered LDS (24 KB) with register prefetch; one barrier per tile.
// ---------------------------------------------------------------------------
__global__ __launch_bounds__(256, 4) void gemm_y0_k(
    const float* __restrict__ W000, const float* __restrict__ W220,
    float* __restrict__ ws) {
  const int* pu = (const int*)(ws + OFF_PU);
  const int* pv = (const int*)(ws + OFF_PV);
  const float* sT = ws + OFF_ST;
  const float* gT = ws + OFF_GT;
  float* y0 = ws + OFF_Y0;

  __shared__ __align__(16) float As[2][KT][64];    // 8 KB
  __shared__ __align__(16) float Bs[2][KT][128];   // 16 KB

  const int tid = threadIdx.x;
  const int bid = blockIdx.x;
  const int ks = bid & 15, mtnt = bid >> 4;        // ks low bits: B-chunk
  const int mt = mtnt >> 1, nt = mtnt & 1;         //   stays XCD-L2-resident
  const int z0 = mt*64, n0 = nt*128;
  const int kbase = ks*CHUNK;
  const int m = tid & 63, w = tid >> 6;
  const int tx = tid & 31, ty = tid >> 5;

  float4 bReg[2];
  float  aReg[4];

  auto load_tile = [&](int t) {
    const int k0 = kbase + t*KT;
    #pragma unroll
    for (int e = 0; e < 2; ++e) {                  // B 16x128, symmetrized
      int idx = e*256 + tid;
      int r = idx >> 5, col = (idx & 31)*4;
      int p = k0 + r;
      float4 val;
      if (p < KPAIR) {
        int u = pu[p], v = pv[p];
        float4 a = *reinterpret_cast<const float4*>(
            &W000[((size_t)u*NS + v)*HH + n0 + col]);
        if (u != v) {
          float4 b = *reinterpret_cast<const float4*>(
              &W000[((size_t)v*NS + u)*HH + n0 + col]);
          val = make_float4(C0F*(a.x+b.x), C0F*(a.y+b.y),
                            C0F*(a.z+b.z), C0F*(a.w+b.w));
        } else {
          val = make_float4(C0F*a.x, C0F*a.y, C0F*a.z, C0F*a.w);
        }
      } else if (p < KPAIR + 36) {
        int u = pu[p], v = pv[p];
        const float sc = C0F*IS5;
        float4 a = *reinterpret_cast<const float4*>(
            &W220[(u*NL2 + v)*HH + n0 + col]);
        if (u != v) {
          float4 b = *reinterpret_cast<const float4*>(
              &W220[(v*NL2 + u)*HH + n0 + col]);
          val = make_float4(sc*(a.x+b.x), sc*(a.y+b.y),
                            sc*(a.z+b.z), sc*(a.w+b.w));
        } else {
          val = make_float4(sc*a.x, sc*a.y, sc*a.z, sc*a.w);
        }
      } else {
        val = make_float4(0.f, 0.f, 0.f, 0.f);
      }
      bReg[e] = val;
    }
    #pragma unroll
    for (int e = 0; e < 4; ++e) {                  // A 16x64 from sT / GramT
      int k = k0 + e*4 + w;                        // wave-uniform row
      float a;
      if (k < KPAIR) {
        a = sT[(size_t)pu[k]*NB + z0 + m] * sT[(size_t)pv[k]*NB + z0 + m];
      } else {
        int q = k - KPAIR;
        a = (q < GLEN) ? gT[(size_t)q*NB + z0 + m] : 0.f;
      }
      aReg[e] = a;
    }
  };
  auto store_tile = [&](int buf) {
    #pragma unroll
    for (int e = 0; e < 2; ++e) {
      int idx = e*256 + tid;
      int r = idx >> 5, col = (idx & 31)*4;
      *reinterpret_cast<float4*>(&Bs[buf][r][col]) = bReg[e];
    }
    #pragma unroll
    for (int e = 0; e < 4; ++e) As[buf][e*4 + w][m] = aReg[e];
  };

  float acc[8][4];
  #pragma unroll
  for (int i = 0; i < 8; ++i)
    #pragma unroll
    for (int j = 0; j < 4; ++j) acc[i][j] = 0.f;

  load_tile(0);
  store_tile(0);
  __syncthreads();

  for (int t = 0; t < NTILES; ++t) {
    if (t + 1 < NTILES) load_tile(t + 1);          // global loads in flight
    const int cur = t & 1;
    #pragma unroll
    for (int kk = 0; kk < KT; ++kk) {
      float4 a0 = *reinterpret_cast<const float4*>(&As[cur][kk][ty*8]);
      float4 a1 = *reinterpret_cast<const float4*>(&As[cur][kk][ty*8+4]);
      float4 bv = *reinterpret_cast<const float4*>(&Bs[cur][kk][tx*4]);
      float am[8] = {a0.x,a0.y,a0.z,a0.w,a1.x,a1.y,a1.z,a1.w};
      float bn[4] = {bv.x,bv.y,bv.z,bv.w};
      #pragma unroll
      for (int mi = 0; mi < 8; ++mi)
        #pragma unroll
        for (int ni = 0; ni < 4; ++ni)
          acc[mi][ni] += am[mi]*bn[ni];
    }
    if (t + 1 < NTILES) store_tile(cur ^ 1);
    __syncthreads();
  }

  #pragma unroll
  for (int mi = 0; mi < 8; ++mi) {
    int z = z0 + ty*8 + mi;
    #pragma unroll
    for (int ni = 0; ni < 4; ++ni)
      atomicAdd(&y0[(size_t)z*HH + n0 + tx*4 + ni], acc[mi][ni]);
  }
}

// ---------------------------------------------------------------------------
// generic fp32 GEMM, row-major, C = A@B. tiles 64x64, KT=32.
// ---------------------------------------------------------------------------
__global__ __launch_bounds__(256) void gemm_rm_k(
    const float* __restrict__ A, const float* __restrict__ B,
    float* __restrict__ C, int M, int N, int K) {
  __shared__ __align__(16) float As[32][68];
  __shared__ __align__(16) float Bs[32][68];
  const int tid = threadIdx.x, tx = tid & 15, ty = tid >> 4;
  const int n0 = blockIdx.x*64, m0 = blockIdx.y*64;
  float acc[4][4];
  #pragma unroll
  for (int i = 0; i < 4; ++i)
    #pragma unroll
    for (int j = 0; j < 4; ++j) acc[i][j] = 0.f;

  for (int k0 = 0; k0 < K; k0 += 32) {
    __syncthreads();
    #pragma unroll
    for (int e = 0; e < 2; ++e) {
      int r = e*32 + (tid >> 3);
      int kc = (tid & 7)*4;
      float4 v = *reinterpret_cast<const float4*>(&A[(size_t)(m0+r)*K + k0 + kc]);
      As[kc+0][r] = v.x; As[kc+1][r] = v.y; As[kc+2][r] = v.z; As[kc+3][r] = v.w;
    }
    #pragma unroll
    for (int e = 0; e < 2; ++e) {
      int idx = e*256 + tid;
      int r = idx >> 4, c4 = idx & 15;
      float4 v = *reinterpret_cast<const float4*>(&B[(size_t)(k0+r)*N + n0 + c4*4]);
      *reinterpret_cast<float4*>(&Bs[r][c4*4]) = v;
    }
    __syncthreads();
    #pragma unroll
    for (int kk = 0; kk < 32; ++kk) {
      float4 av = *reinterpret_cast<const float4*>(&As[kk][ty*4]);
      float4 bv = *reinterpret_cast<const float4*>(&Bs[kk][tx*4]);
      float am[4] = {av.x, av.y, av.z, av.w};
      float bn[4] = {bv.x, bv.y, bv.z, bv.w};
      #pragma unroll
      for (int i = 0; i < 4; ++i)
        #pragma unroll
        for (int j = 0; j < 4; ++j) acc[i][j] += am[i]*bn[j];
    }
  }
  #pragma unroll
  for (int i = 0; i < 4; ++i) {
    float4 v = make_float4(acc[i][0], acc[i][1], acc[i][2], acc[i][3]);
    *reinterpret_cast<float4*>(&C[(size_t)(m0 + ty*4 + i)*N + n0 + tx*4]) = v;
  }
}

// ---------------------------------------------------------------------------
// mega: per 8-z block, fused y2 (A12-part + W222 term) + tp2 tail -> out[z,5]
// ---------------------------------------------------------------------------
__global__ __launch_bounds__(256) void mega_k(
    const float* __restrict__ scalars, const float* __restrict__ W022,
    const float* __restrict__ W202, const float* __restrict__ ws,
    float* __restrict__ out) {
  const float* tg    = ws + OFF_T;
  const float* W222c = ws + OFF_W222;
  const float* VC    = ws + OFF_VC;
  const float* acp   = ws + OFF_ACP;
  const float* c222g = ws + OFF_C222;

  __shared__ float ts[8][40];
  __shared__ float c2s[125];
  __shared__ __align__(16) float sb[8][128];
  __shared__ __align__(16) float ovl[10240];   // tC[1600] + Rs[2560] | y2s[10240]
  float* tC  = ovl;                 // tC(z,v,ik)   = tC[z*200 + v*25 + ik]
  float* RsF = ovl + 1600;          // Rs(uv,z,k)   = RsF[uv*40 + z*5 + k]
  float* y2s = ovl;                 // y2(z,i,u)    = y2s[z*1280 + i*256 + u]

  const int tid = threadIdx.x;
  const int zg0 = blockIdx.x*8;
  const int lane = tid & 63, wv = tid >> 6;

  // stage ts, c2s, sb   (ts is 320 entries > blockDim: MUST grid-stride)
  if (tid < 125) c2s[tid] = c222g[tid];
  for (int r = tid; r < 320; r += 256) {
    int z = r/40, c = r - z*40;
    ts[z][c] = tg[(size_t)(zg0 + z)*40 + c];
  }
  {
    int z = tid >> 5, c4 = tid & 31;
    float4 v = reinterpret_cast<const float4*>(scalars + (size_t)(zg0 + z)*NS)[c4];
    sb[z][c4*4+0] = v.x; sb[z][c4*4+1] = v.y;
    sb[z][c4*4+2] = v.z; sb[z][c4*4+3] = v.w;
  }
  __syncthreads();

  for (int idx = tid; idx < 1600; idx += 256) {    // tC = C222 . t
    int z = idx/200, r = idx - z*200, v = r/25, ik = r - v*25;
    int i = ik/5, k = ik - i*5;
    float a = 0.f;
    #pragma unroll
    for (int j = 0; j < 5; ++j) a += c2s[(i*5+j)*5 + k]*ts[z][v*5+j];
    tC[idx] = a;
  }
  __syncthreads();
  for (int idx = tid; idx < 2560; idx += 256) {    // Rs = t x C222 x t
    int uv = idx/40, r = idx - uv*40, z = r/5, k = r - z*5;
    int u = uv >> 3, v = uv & 7;
    float a = 0.f;
    #pragma unroll
    for (int ii = 0; ii < 5; ++ii) a += ts[z][u*5+ii]*tC[z*200 + v*25 + ii*5 + k];
    RsF[idx] = a;
  }
  __syncthreads();

  float acc[8][5];                                 // y2[z,k, w=tid]
  #pragma unroll
  for (int z = 0; z < 8; ++z)
    #pragma unroll
    for (int k = 0; k < 5; ++k) acc[z][k] = 0.f;

  // A12 part: sum_u s[z,u]*W1[u,vp*256+tid] (W1 read raw from W022/W202),
  // contracted with t.  Scale C2F*IS5 folded at the contract.
  for (int vg = 0; vg < 4; ++vg) {
    float av[4][8];
    #pragma unroll
    for (int vi = 0; vi < 4; ++vi)
      #pragma unroll
      for (int z = 0; z < 8; ++z) av[vi][z] = 0.f;
    for (int u4 = 0; u4 < 128; u4 += 4) {
      float4 szv[8];
      #pragma unroll
      for (int z = 0; z < 8; ++z) szv[z] = *reinterpret_cast<const float4*>(&sb[z][u4]);
      #pragma unroll
      for (int uu = 0; uu < 4; ++uu) {
        int u = u4 + uu;
        #pragma unroll
        for (int vi = 0; vi < 4; ++vi) {
          float w1v = (vg < 2)
            ? W022[((size_t)u*NL2 + (vg*4+vi))*HH + tid]
            : W202[((size_t)((vg-2)*4+vi)*NS + u)*HH + tid];
          #pragma unroll
          for (int z = 0; z < 8; ++z) {
            float su = (uu==0)?szv[z].x:(uu==1)?szv[z].y:(uu==2)?szv[z].z:szv[z].w;
            av[vi][z] += su*w1v;
          }
        }
      }
    }
    #pragma unroll
    for (int vi = 0; vi < 4; ++vi) {
      int vmap = (vg*4 + vi) & 7;
      #pragma unroll
      for (int z = 0; z < 8; ++z) {
        float avs = (C2F*IS5)*av[vi][z];
        #pragma unroll
        for (int k = 0; k < 5; ++k)
          acc[z][k] += avs*ts[z][vmap*5+k];
      }
    }
  }

  // W222 term
  for (int uv = 0; uv < 64; ++uv) {
    float wvv = W222c[uv*256 + tid];
    #pragma unroll
    for (int c4 = 0; c4 < 10; ++c4) {
      float4 rv = *reinterpret_cast<const float4*>(&RsF[uv*40 + c4*4]);
      acc[(c4*4+0)/5][(c4*4+0)%5] += wvv*rv.x;
      acc[(c4*4+1)/5][(c4*4+1)%5] += wvv*rv.y;
      acc[(c4*4+2)/5][(c4*4+2)%5] += wvv*rv.z;
      acc[(c4*4+3)/5][(c4*4+3)%5] += wvv*rv.w;
    }
  }

  __syncthreads();                                 // tC/Rs dead; overlay
  #pragma unroll
  for (int z = 0; z < 8; ++z)
    #pragma unroll
    for (int k = 0; k < 5; ++k)
      y2s[z*1280 + k*256 + tid] = acc[z][k];
  __syncthreads();

  // Hz[z,i,v] = sum_u y2[z,i,u]*VC[u,v]; wave wv owns z = wv*2 + {0,1}
  float hacc[2][5][4];
  #pragma unroll
  for (int zz = 0; zz < 2; ++zz)
    #pragma unroll
    for (int i = 0; i < 5; ++i)
      #pragma unroll
      for (int j = 0; j < 4; ++j) hacc[zz][i][j] = 0.f;

  for (int u4 = 0; u4 < 256; u4 += 4) {
    float vc[4][4];
    #pragma unroll
    for (int uu = 0; uu < 4; ++uu)
      #pragma unroll
      for (int j = 0; j < 4; ++j)
        vc[uu][j] = VC[(size_t)(u4+uu)*256 + lane + 64*j];
    #pragma unroll
    for (int zz = 0; zz < 2; ++zz) {
      int z = wv*2 + zz;
      #pragma unroll
      for (int i = 0; i < 5; ++i) {
        float4 yv = *reinterpret_cast<const float4*>(&y2s[z*1280 + i*256 + u4]);
        float ya[4] = {yv.x, yv.y, yv.z, yv.w};
        #pragma unroll
        for (int uu = 0; uu < 4; ++uu)
          #pragma unroll
          for (int j = 0; j < 4; ++j)
            hacc[zz][i][j] += ya[uu]*vc[uu][j];
      }
    }
  }

  // out[z,k] = sum_v ac'[z,v]*y2[z,k,v] + sum_{i,jp} C[i,jp,k]*Hz[z,i,v]*y2[z,jp,v]
  float outp[2][5];
  #pragma unroll
  for (int zz = 0; zz < 2; ++zz)
    #pragma unroll
    for (int k = 0; k < 5; ++k) outp[zz][k] = 0.f;

  for (int j = 0; j < 4; ++j) {
    int v = lane + 64*j;
    #pragma unroll
    for (int zz = 0; zz < 2; ++zz) {
      int z = wv*2 + zz;
      float y2v[5];
      #pragma unroll
      for (int jp = 0; jp < 5; ++jp) y2v[jp] = y2s[z*1280 + jp*256 + v];
      float avv = acp[(size_t)(zg0 + z)*256 + v];
      #pragma unroll
      for (int k = 0; k < 5; ++k) outp[zz][k] += avv*y2v[k];
      #pragma unroll
      for (int i = 0; i < 5; ++i) {
        float hv = hacc[zz][i][j];
        #pragma unroll
        for (int jp = 0; jp < 5; ++jp) {
          float pj = hv*y2v[jp];
          #pragma unroll
          for (int k = 0; k < 5; ++k)
            outp[zz][k] += pj*c2s[i*25 + jp*5 + k];
        }
      }
    }
  }

  #pragma unroll
  for (int zz = 0; zz < 2; ++zz)
    #pragma unroll
    for (int k = 0; k < 5; ++k) {
      float vsum = outp[zz][k];
      #pragma unroll
      for (int off = 32; off > 0; off >>= 1) vsum += __shfl_xor(vsum, off, 64);
      if (lane == 0) out[(size_t)(zg0 + wv*2 + zz)*5 + k] = vsum;
    }
}

// ---------------------------------------------------------------------------
extern "C" void kernel_launch(void* const* d_in, const int* in_sizes, int n_in,
                              void* d_out, int out_size, void* d_ws, size_t ws_size,
                              hipStream_t stream) {
  (void)in_sizes; (void)n_in; (void)out_size;
  const float* scalars = (const float*)d_in[0];
  const float* kt2s    = (const float*)d_in[1];
  const float* W000    = (const float*)d_in[2];
  const float* W220    = (const float*)d_in[3];
  const float* W022    = (const float*)d_in[4];
  const float* W202    = (const float*)d_in[5];
  const float* W222    = (const float*)d_in[6];
  const float* V022    = (const float*)d_in[7];
  const float* V202    = (const float*)d_in[8];
  const float* V222    = (const float*)d_in[9];
  float* out = (float*)d_out;
  float* ws  = (float*)d_ws;
  if (ws_size < WS_FLOATS*sizeof(float)) return;  // needs ~6.75 MB scratch

  prep_k<<<1025, 256, 0, stream>>>(scalars, kt2s, W222, V022, V202, V222, ws);
  gemm_y0_k<<<1024, 256, 0, stream>>>(W000, W220, ws);
  gemm_rm_k<<<dim3(4, 32), 256, 0, stream>>>(ws + OFF_Y0, ws + OFF_VBS,
                                             (float*)(ws + OFF_ACP), 2048, 256, 256);
  mega_k<<<256, 256, 0, stream>>>(scalars, W022, W202, ws, out);
}